// Round 10
// baseline (103.468 us; speedup 1.0000x reference)
//
#include <hip/hip_runtime.h>

typedef __attribute__((ext_vector_type(2))) __fp16 fp16x2;
typedef __attribute__((ext_vector_type(4))) _Float16 half4;
typedef __attribute__((ext_vector_type(8))) _Float16 half8;
typedef __attribute__((ext_vector_type(4))) float f32x4;

#define T_STEPS 24
#define N_NODES 325
#define RS_T 20800       // N*H elements per t
#define B_STRIDE 499200  // T*N*H elements per b
#define HLAST_OFF 31948800

__device__ __forceinline__ float fsigmoid(float x) {
    return __builtin_amdgcn_rcpf(1.0f + __expf(-x));
}
__device__ __forceinline__ float ftanh_f(float x) {
    return 1.0f - 2.0f * __builtin_amdgcn_rcpf(1.0f + __expf(2.0f * x));
}
__device__ __forceinline__ half8 cvt8p(f32x4 a, f32x4 b) {
    union { half8 h8; fp16x2 h2[4]; } u;
    u.h2[0] = __builtin_amdgcn_cvt_pkrtz(a[0], a[1]);
    u.h2[1] = __builtin_amdgcn_cvt_pkrtz(a[2], a[3]);
    u.h2[2] = __builtin_amdgcn_cvt_pkrtz(b[0], b[1]);
    u.h2[3] = __builtin_amdgcn_cvt_pkrtz(b[2], b[3]);
    return u.h8;
}
__device__ __forceinline__ void pin(half8& x) { asm volatile("" : "+v"(x)); }
__device__ __forceinline__ void pin(f32x4& x) { asm volatile("" : "+v"(x)); }

// Register-resident weights (pinned, no weight LDS), 32 rows/block, 4 waves.
// Wave wv owns gate cols {c0, 64+c0, 128+c0}, c0 = 16*wv, for BOTH 16-row
// A-tiles. LDS only for the tiny double-buffered h exchange (8 KB).
// 650 blocks @ 2 blocks/CU -> 1.27 generations (vs 2.5 before).
__global__ __launch_bounds__(256, 2) void gru_regw_kernel(
    const float* __restrict__ data,   // [B,T,N,F]
    const float* __restrict__ h0,     // [B,N,H]
    const float* __restrict__ w_ih,   // [192,64]
    const float* __restrict__ w_hh,   // [192,64]
    const float* __restrict__ b_ih,   // [192]
    const float* __restrict__ b_hh,   // [192]
    float* __restrict__ out)          // [B,T,N,H] ++ [B,N,H]
{
    const int tid  = threadIdx.x;
    const int lane = tid & 63;
    const int wv   = tid >> 6;        // 0..3
    const int cl   = lane & 15;
    const int kg   = lane >> 4;
    const int c0   = wv * 16;
    const int row0 = blockIdx.x * 32;

    __shared__ __align__(16) char hlds[2][32 * 128];  // dbuf h, f16 swizzled

    // ---- weight B-frags: straight from global, f16, PINNED in registers ----
    // frag for gate g, k-slice s: lane holds W[n = g*64+c0+cl][k = s*32+kg*8 .. +8]
    half8 wf[3][2], uf[3][2];   // [gate][s]: w_ih, w_hh
#pragma unroll
    for (int g = 0; g < 3; ++g) {
        const float* pih = w_ih + (g * 64 + c0 + cl) * 64 + kg * 8;
        const float* phh = w_hh + (g * 64 + c0 + cl) * 64 + kg * 8;
#pragma unroll
        for (int s = 0; s < 2; ++s) {
            wf[g][s] = cvt8p(*(const f32x4*)(pih + s * 32), *(const f32x4*)(pih + s * 32 + 4));
            uf[g][s] = cvt8p(*(const f32x4*)(phh + s * 32), *(const f32x4*)(phh + s * 32 + 4));
            pin(wf[g][s]); pin(uf[g][s]);
        }
    }

    // ---- bias splats as MFMA C-init (pinned) ----
    const float bc0 = b_ih[      c0 + cl] + b_hh[      c0 + cl];
    const float bc1 = b_ih[ 64 + c0 + cl] + b_hh[ 64 + c0 + cl];
    const float bi2 = b_ih[128 + c0 + cl];
    const float bh2 = b_hh[128 + c0 + cl];
    f32x4 bR4  = {bc0, bc0, bc0, bc0};
    f32x4 bZ4  = {bc1, bc1, bc1, bc1};
    f32x4 bNX4 = {bi2, bi2, bi2, bi2};
    f32x4 bNH4 = {bh2, bh2, bh2, bh2};
    pin(bR4); pin(bZ4); pin(bNX4); pin(bNH4);

    // ---- stage h0 (32 rows x 64 cols) into hlds[0], f16 swizzled ----
#pragma unroll
    for (int it = 0; it < 2; ++it) {
        const int c = it * 256 + tid;             // 0..511
        const int mrow = c >> 4, c4 = (c & 15) * 4;
        const f32x4 v = *(const f32x4*)(h0 + (row0 + mrow) * 64 + c4);
        union { half4 h4; fp16x2 h2[2]; } u;
        u.h2[0] = __builtin_amdgcn_cvt_pkrtz(v[0], v[1]);
        u.h2[1] = __builtin_amdgcn_cvt_pkrtz(v[2], v[3]);
        const int off = mrow * 128 + ((c4 * 2) ^ ((mrow & 7) << 4));
        *(half4*)(&hlds[0][0] + off) = u.h4;
    }

    // ---- h A-frag LDS offsets (rows cl and cl+16) ----
    const int hsw  = (cl & 7) << 4;
    const int hr00 = cl * 128        + ((     kg * 16) ^ hsw);
    const int hr01 = cl * 128        + ((64 + kg * 16) ^ hsw);
    const int hr10 = (cl + 16) * 128 + ((     kg * 16) ^ hsw);
    const int hr11 = (cl + 16) * 128 + ((64 + kg * 16) ^ hsw);

    // ---- per-lane h master copies & addressing, 2 tiles ----
    float hreg[2][4];
    int obase[2][4];
#pragma unroll
    for (int tt = 0; tt < 2; ++tt)
#pragma unroll
        for (int r = 0; r < 4; ++r) {
            const int row = row0 + tt * 16 + kg * 4 + r;
            hreg[tt][r] = h0[row * 64 + c0 + cl];
            const int b = row / N_NODES, n = row % N_NODES;
            obase[tt][r] = b * B_STRIDE + n * 64 + c0 + cl;
        }
    int xbase[2];
#pragma unroll
    for (int tt = 0; tt < 2; ++tt) {
        const int xrow = row0 + tt * 16 + cl;
        xbase[tt] = (xrow / N_NODES) * B_STRIDE + (xrow % N_NODES) * 64;
    }

    // ---- x: t=0 current + t=1 prefetch in flight ----
    half8 xcur[2][2];
    f32x4 xpf[2][4];
#pragma unroll
    for (int tt = 0; tt < 2; ++tt) {
        f32x4 t0[4];
#pragma unroll
        for (int q = 0; q < 4; ++q)
            t0[q] = *(const f32x4*)(data + xbase[tt] + (q >> 1) * 32 + kg * 8 + (q & 1) * 4);
        xcur[tt][0] = cvt8p(t0[0], t0[1]);
        xcur[tt][1] = cvt8p(t0[2], t0[3]);
#pragma unroll
        for (int q = 0; q < 4; ++q)
            xpf[tt][q] = *(const f32x4*)(data + xbase[tt] + RS_T + (q >> 1) * 32 + kg * 8 + (q & 1) * 4);
    }

    __syncthreads();   // h0 staged

#pragma unroll 1
    for (int t = 0; t < T_STEPS; ++t) {
        const int cb = t & 1;

        // h A-frags (only post-barrier LDS dependency: 4 ds_read_b128)
        const half8 hA00 = *(const half8*)(&hlds[cb][0] + hr00);
        const half8 hA01 = *(const half8*)(&hlds[cb][0] + hr01);
        const half8 hA10 = *(const half8*)(&hlds[cb][0] + hr10);
        const half8 hA11 = *(const half8*)(&hlds[cb][0] + hr11);

        // next x arrives; issue t+2 prefetch
        half8 xnext[2][2];
        const int tl = (t + 2 < T_STEPS) ? t + 2 : T_STEPS - 1;
#pragma unroll
        for (int tt = 0; tt < 2; ++tt) {
            xnext[tt][0] = cvt8p(xpf[tt][0], xpf[tt][1]);
            xnext[tt][1] = cvt8p(xpf[tt][2], xpf[tt][3]);
#pragma unroll
            for (int q = 0; q < 4; ++q)
                xpf[tt][q] = *(const f32x4*)(data + xbase[tt] + tl * RS_T +
                                             (q >> 1) * 32 + kg * 8 + (q & 1) * 4);
        }

        // ---- 24 MFMAs: 2 tiles sharing the register-resident weights ----
        f32x4 aR[2], aZ[2], aNX[2], aNH[2];
#pragma unroll
        for (int tt = 0; tt < 2; ++tt) {
            const half8 h0f = tt ? hA10 : hA00;
            const half8 h1f = tt ? hA11 : hA01;
            aR[tt]  = __builtin_amdgcn_mfma_f32_16x16x32_f16(xcur[tt][0], wf[0][0], bR4,  0, 0, 0);
            aZ[tt]  = __builtin_amdgcn_mfma_f32_16x16x32_f16(xcur[tt][0], wf[1][0], bZ4,  0, 0, 0);
            aNX[tt] = __builtin_amdgcn_mfma_f32_16x16x32_f16(xcur[tt][0], wf[2][0], bNX4, 0, 0, 0);
            aNH[tt] = __builtin_amdgcn_mfma_f32_16x16x32_f16(h0f,         uf[2][0], bNH4, 0, 0, 0);
            aR[tt]  = __builtin_amdgcn_mfma_f32_16x16x32_f16(xcur[tt][1], wf[0][1], aR[tt],  0, 0, 0);
            aZ[tt]  = __builtin_amdgcn_mfma_f32_16x16x32_f16(xcur[tt][1], wf[1][1], aZ[tt],  0, 0, 0);
            aNX[tt] = __builtin_amdgcn_mfma_f32_16x16x32_f16(xcur[tt][1], wf[2][1], aNX[tt], 0, 0, 0);
            aNH[tt] = __builtin_amdgcn_mfma_f32_16x16x32_f16(h1f,         uf[2][1], aNH[tt], 0, 0, 0);
            aR[tt]  = __builtin_amdgcn_mfma_f32_16x16x32_f16(h0f,         uf[0][0], aR[tt],  0, 0, 0);
            aZ[tt]  = __builtin_amdgcn_mfma_f32_16x16x32_f16(h0f,         uf[1][0], aZ[tt],  0, 0, 0);
            aR[tt]  = __builtin_amdgcn_mfma_f32_16x16x32_f16(h1f,         uf[0][1], aR[tt],  0, 0, 0);
            aZ[tt]  = __builtin_amdgcn_mfma_f32_16x16x32_f16(h1f,         uf[1][1], aZ[tt],  0, 0, 0);
        }

        // ---- gates + update + store + publish ----
        float hn[2][4];
#pragma unroll
        for (int tt = 0; tt < 2; ++tt)
#pragma unroll
            for (int r = 0; r < 4; ++r) {
                const float rg = fsigmoid(aR[tt][r]);
                const float zg = fsigmoid(aZ[tt][r]);
                const float cd = ftanh_f(aNX[tt][r] + rg * aNH[tt][r]);
                hn[tt][r] = cd + zg * (hreg[tt][r] - cd);
                hreg[tt][r] = hn[tt][r];
                out[t * RS_T + obase[tt][r]] = hn[tt][r];
            }

        if (t + 1 < T_STEPS) {
            const int nb = (t + 1) & 1;
#pragma unroll
            for (int tt = 0; tt < 2; ++tt)
#pragma unroll
                for (int r = 0; r < 4; ++r) {
                    const int mrow = tt * 16 + kg * 4 + r;
                    const int off = mrow * 128 + (((c0 + cl) * 2) ^ ((mrow & 7) << 4));
                    *(_Float16*)(&hlds[nb][0] + off) = (_Float16)hn[tt][r];
                }
            asm volatile("s_waitcnt lgkmcnt(0)" ::: "memory");
            __builtin_amdgcn_s_barrier();
            __builtin_amdgcn_sched_barrier(0);
        }
#pragma unroll
        for (int tt = 0; tt < 2; ++tt) {
            xcur[tt][0] = xnext[tt][0];
            xcur[tt][1] = xnext[tt][1];
        }
    }

    // h_last
#pragma unroll
    for (int tt = 0; tt < 2; ++tt)
#pragma unroll
        for (int r = 0; r < 4; ++r) {
            const int row = row0 + tt * 16 + kg * 4 + r;
            out[HLAST_OFF + row * 64 + c0 + cl] = hreg[tt][r];
        }
}

extern "C" void kernel_launch(void* const* d_in, const int* in_sizes, int n_in,
                              void* d_out, int out_size, void* d_ws, size_t ws_size,
                              hipStream_t stream) {
    const float* data = (const float*)d_in[1];
    const float* h0   = (const float*)d_in[2];
    const float* w_ih = (const float*)d_in[3];
    const float* w_hh = (const float*)d_in[4];
    const float* b_ih = (const float*)d_in[5];
    const float* b_hh = (const float*)d_in[6];
    float* out = (float*)d_out;

    // 20800 rows / 32 per block = 650 blocks, 4 waves each
    gru_regw_kernel<<<dim3(650), dim3(256), 0, stream>>>(
        data, h0, w_ih, w_hh, b_ih, b_hh, out);
}